// Round 18
// baseline (199.401 us; speedup 1.0000x reference)
//
#include <hip/hip_runtime.h>

constexpr int B_ = 4;
constexpr int N_ = 2048;
constexpr int NFEAT_ = 256;
constexpr int NHEADS_ = 8;
constexpr float SLOPE_ = 0.1f;
constexpr float L2E = 1.4426950408889634f;   // log2(e)

typedef __attribute__((ext_vector_type(8))) __fp16 f16x8;
typedef __attribute__((ext_vector_type(4))) __fp16 f16x4;
typedef __attribute__((ext_vector_type(2))) __fp16 f16x2;
typedef __attribute__((ext_vector_type(4))) float f32x4;

__device__ __forceinline__ f16x8 pack8(const float* v) {
  union { f16x2 h2[4]; f16x8 h8; } u;
  u.h2[0] = __builtin_amdgcn_cvt_pkrtz(v[0], v[1]);
  u.h2[1] = __builtin_amdgcn_cvt_pkrtz(v[2], v[3]);
  u.h2[2] = __builtin_amdgcn_cvt_pkrtz(v[4], v[5]);
  u.h2[3] = __builtin_amdgcn_cvt_pkrtz(v[6], v[7]);
  return u.h8;
}
__device__ __forceinline__ f16x4 pack4(float a, float b, float c, float d) {
  union { f16x2 h2[2]; f16x4 h4; } u;
  u.h2[0] = __builtin_amdgcn_cvt_pkrtz(a, b);
  u.h2[1] = __builtin_amdgcn_cvt_pkrtz(c, d);
  return u.h4;
}

// ---------------------------------------------------------------------------
// Fused prep: blocks [0,4096) packmask; [4096,4160) prepWh; [4160,4192) prepWo
// ---------------------------------------------------------------------------
__global__ __launch_bounds__(256) void k_prep(
    const int* __restrict__ adj, unsigned short* __restrict__ mask2,
    const float* __restrict__ Wh, __fp16* __restrict__ WhB,
    const float* __restrict__ Wo, __fp16* __restrict__ WoB)
{
  const int bid = blockIdx.x;
  const int l = threadIdx.x & 63;
  if (bid < 4096) {
    const size_t gw = ((size_t)bid * 256 + threadIdx.x) >> 6;
    const int jt = (int)(gw & 31);
    const int ig16 = (int)((gw >> 5) & 127);
    const int b = (int)(gw >> 12);
    const int q = l >> 4, c15 = l & 15;
    const int* base = adj + ((size_t)b * N_ + ig16 * 16) * N_ + jt * 64 + l;
    unsigned int msk = 0;
    #pragma unroll
    for (int r = 0; r < 16; ++r) {
      int a = base[(size_t)r * N_];
      unsigned long long bal = __ballot(a > 0);
      unsigned int v = (unsigned int)((bal >> (q * 8)) & 0xffull)
                     | ((unsigned int)((bal >> (q * 8 + 32)) & 0xffull) << 8);
      if (r == c15) msk = v;
    }
    mask2[gw * 64 + l] = (unsigned short)msk;
  } else if (bid < 4160) {
    int s = (int)(((bid - 4096) * 256 + threadIdx.x) >> 6);   // 0..255
    int h = s >> 5, ks = (s >> 2) & 7, ft = s & 3;
    const float* src = Wh + ((size_t)h * 256 + ks * 32 + (l >> 4) * 8) * 64 + ft * 16 + (l & 15);
    float v[8];
    #pragma unroll
    for (int j = 0; j < 8; ++j) v[j] = src[(size_t)j * 64];
    *(f16x8*)(WhB + (size_t)s * 512 + l * 8) = pack8(v);
  } else {
    int s = (int)(((bid - 4160) * 256 + threadIdx.x) >> 6);   // 0..127
    int ks = s >> 3, ft = s & 7;
    const float* src = Wo + ((size_t)ks * 32 + (l >> 4) * 8) * 128 + ft * 16 + (l & 15);
    float v[8];
    #pragma unroll
    for (int j = 0; j < 8; ++j) v[j] = src[(size_t)j * 128];
    *(f16x8*)(WoB + (size_t)s * 512 + l * 8) = pack8(v);
  }
}

// ---------------------------------------------------------------------------
// GEMM1 (MFMA), F-SPLIT: block = 16 n-rows x 128 f (ONE head-pair hp).
// Grid 2048 blocks (4x R17) -> ~32 waves/CU; per wave acc[2], only 16
// B-fragment loads (vs 64) -> short critical path + free VGPRs to hoist.
// ---------------------------------------------------------------------------
__global__ __launch_bounds__(256, 4) void k_gemm1(
    const float* __restrict__ x, const __fp16* __restrict__ WhB,
    const float* __restrict__ ah,
    __fp16* __restrict__ hB1, float* __restrict__ s1h, float* __restrict__ s2h)
{
  constexpr int XP = 264;
  __shared__ __fp16 xs[16 * XP];               // 8.25 KB
  __shared__ __fp16 hT[128 * 16];              // 4 KB
  __shared__ float sd1[4][16], sd2[4][16];

  const int t = threadIdx.x;
  const int bid = blockIdx.x;
  const int hp = bid & 3;                      // head pair
  const int ng = (bid >> 2) & 127;
  const int b  = bid >> 9;
  const int n0 = ng * 16;

  {  // stage x -> f16
    int r = t >> 4, k0 = (t & 15) * 16;
    const float* src = x + ((size_t)(b * N_) + n0 + r) * NFEAT_ + k0;
    float v0[8], v1[8];
    *(float4*)&v0[0] = *(const float4*)(src);
    *(float4*)&v0[4] = *(const float4*)(src + 4);
    *(float4*)&v1[0] = *(const float4*)(src + 8);
    *(float4*)&v1[4] = *(const float4*)(src + 12);
    *(f16x8*)&xs[r * XP + k0] = pack8(v0);
    *(f16x8*)&xs[r * XP + k0 + 8] = pack8(v1);
  }
  __syncthreads();

  const int w = t >> 6, l = t & 63;
  const int quad = l >> 4, c15 = l & 15;
  const int hl = w >> 1, fp = w & 1;           // wave -> (head-local, ft-pair)
  const int head = hp * 2 + hl;

  f32x4 acc[2];
  acc[0] = (f32x4){0.f, 0.f, 0.f, 0.f};
  acc[1] = (f32x4){0.f, 0.f, 0.f, 0.f};

  for (int ks = 0; ks < 8; ++ks) {
    f16x8 af = *(const f16x8*)&xs[c15 * XP + ks * 32 + quad * 8];
    #pragma unroll
    for (int tt = 0; tt < 2; ++tt) {
      int ft = fp * 2 + tt;
      f16x8 bf = *(const f16x8*)(WhB +
          ((((size_t)head * 8 + ks) * 4 + ft) * 512) + l * 8);
      acc[tt] = __builtin_amdgcn_mfma_f32_16x16x32_f16(af, bf, acc[tt], 0, 0, 0);
    }
  }

  // partial s-dots over this wave's 2 ftiles
  {
    float a1v[2], a2v[2];
    #pragma unroll
    for (int tt = 0; tt < 2; ++tt) {
      int ft = fp * 2 + tt;
      a1v[tt] = ah[head * 128 + ft * 16 + c15] * L2E;
      a2v[tt] = ah[head * 128 + 64 + ft * 16 + c15] * L2E;
    }
    #pragma unroll
    for (int r = 0; r < 4; ++r) {
      float v1 = acc[0][r] * a1v[0] + acc[1][r] * a1v[1];
      float v2 = acc[0][r] * a2v[0] + acc[1][r] * a2v[1];
      #pragma unroll
      for (int off = 1; off < 16; off <<= 1) {
        v1 += __shfl_xor(v1, off, 64);
        v2 += __shfl_xor(v2, off, 64);
      }
      if (c15 == 0) { sd1[w][quad * 4 + r] = v1; sd2[w][quad * 4 + r] = v2; }
    }
  }

  // transpose into hT[f_local][n]
  #pragma unroll
  for (int tt = 0; tt < 2; ++tt) {
    int fl = hl * 64 + (fp * 2 + tt) * 16 + c15;
    *(f16x4*)&hT[fl * 16 + quad * 4] =
        pack4(acc[tt][0], acc[tt][1], acc[tt][2], acc[tt][3]);
  }
  __syncthreads();

  // s-dot combine: head hp*2 = waves 0+1, head hp*2+1 = waves 2+3
  if (t < 16)
    s1h[(size_t)(b * 8 + hp * 2) * N_ + n0 + t] = sd1[0][t] + sd1[1][t];
  else if (t < 32) { int r = t - 16;
    s2h[(size_t)(b * 8 + hp * 2) * N_ + n0 + r] = sd2[0][r] + sd2[1][r]; }
  else if (t < 48) { int r = t - 32;
    s1h[(size_t)(b * 8 + hp * 2 + 1) * N_ + n0 + r] = sd1[2][r] + sd1[3][r]; }
  else if (t < 64) { int r = t - 48;
    s2h[(size_t)(b * 8 + hp * 2 + 1) * N_ + n0 + r] = sd2[2][r] + sd2[3][r]; }

  // hB1 stores: 256 slots (128 f x 2 octs), 1 per thread
  {
    int c15v = t & 15, oct = (t >> 4) & 1, ftl = t >> 5;   // [0,8)
    int hl2 = ftl >> 2, ft = ftl & 3;
    int headg = hp * 2 + hl2;
    f16x8 v = *(const f16x8*)&hT[(ftl * 16 + c15v) * 16 + oct * 8];
    int base_oct = (n0 >> 3) & 3;
    int lane0 = (base_oct + oct) * 16 + c15v;
    *(f16x8*)(hB1 +
        ((((size_t)(b * 8 + headg) * 64 + (n0 >> 5)) * 4 + ft) * 512) + lane0 * 8) = v;
  }
}

// ---------------------------------------------------------------------------
// GEMM2 (MFMA), F-SPLIT: block = 16 n-rows x 64 f (fs half). Grid 1024.
// Per wave: acc[1], 16 B-loads. Partial s-dots (over 64 f) -> s1oP/s2oP[fs];
// att2 sums both halves at its staging step.
// ---------------------------------------------------------------------------
__global__ __launch_bounds__(256, 4) void k_gemm2(
    const __fp16* __restrict__ g1, const __fp16* __restrict__ WoB,
    const float* __restrict__ ao,
    __fp16* __restrict__ hB2, float* __restrict__ s1oP, float* __restrict__ s2oP)
{
  constexpr int GP = 520;
  __shared__ __fp16 gs[16 * GP];               // 16.25 KB
  __shared__ __fp16 hT[64 * 16];               // 2 KB
  __shared__ float sd1[4][16], sd2[4][16];

  const int t = threadIdx.x;
  const int bid = blockIdx.x;
  const int fs = bid & 1;
  const int ng = (bid >> 1) & 127;
  const int b = bid >> 8;
  const int n0 = ng * 16;

  {
    int r = t >> 4, k0 = (t & 15) * 32;
    const __fp16* src = g1 + ((size_t)(b * N_) + n0 + r) * 512 + k0;
    #pragma unroll
    for (int i = 0; i < 4; ++i)
      *(f16x8*)&gs[r * GP + k0 + i * 8] = *(const f16x8*)(src + i * 8);
  }
  __syncthreads();

  const int w = t >> 6, l = t & 63;
  const int quad = l >> 4, c15 = l & 15;
  const int ft = fs * 4 + w;                   // global ftile [0,8)

  f32x4 acc = (f32x4){0.f, 0.f, 0.f, 0.f};
  for (int ks = 0; ks < 16; ++ks) {
    f16x8 af = *(const f16x8*)&gs[c15 * GP + ks * 32 + quad * 8];
    f16x8 bf = *(const f16x8*)(WoB + (((size_t)ks * 8 + ft) * 512) + l * 8);
    acc = __builtin_amdgcn_mfma_f32_16x16x32_f16(af, bf, acc, 0, 0, 0);
  }

  // partial s-dots over this wave's 16 f
  {
    float a1v = ao[ft * 16 + c15] * L2E;
    float a2v = ao[128 + ft * 16 + c15] * L2E;
    #pragma unroll
    for (int r = 0; r < 4; ++r) {
      float v1 = acc[r] * a1v, v2 = acc[r] * a2v;
      #pragma unroll
      for (int off = 1; off < 16; off <<= 1) {
        v1 += __shfl_xor(v1, off, 64);
        v2 += __shfl_xor(v2, off, 64);
      }
      if (c15 == 0) { sd1[w][quad * 4 + r] = v1; sd2[w][quad * 4 + r] = v2; }
    }
  }

  // transpose
  *(f16x4*)&hT[(w * 16 + c15) * 16 + quad * 4] =
      pack4(acc[0], acc[1], acc[2], acc[3]);
  __syncthreads();

  if (t < 16)
    s1oP[(size_t)fs * (B_ * N_) + (size_t)b * N_ + n0 + t] =
        sd1[0][t] + sd1[1][t] + sd1[2][t] + sd1[3][t];
  else if (t < 32) {
    int r = t - 16;
    s2oP[(size_t)fs * (B_ * N_) + (size_t)b * N_ + n0 + r] =
        sd2[0][r] + sd2[1][r] + sd2[2][r] + sd2[3][r];
  }

  // hB2 stores: 128 slots
  if (t < 128) {
    int c15v = t & 15, oct = (t >> 4) & 1, ftl = t >> 5;   // [0,4)
    int ftg = fs * 4 + ftl;
    f16x8 v = *(const f16x8*)&hT[(ftl * 16 + c15v) * 16 + oct * 8];
    int base_oct = (n0 >> 3) & 3;
    int lane0 = (base_oct + oct) * 16 + c15v;
    *(f16x8*)(hB2 +
        (((size_t)(b * 64 + (n0 >> 5)) * 8 + ftg) * 512) + lane0 * 8) = v;
  }
}

// ---------------------------------------------------------------------------
// ATT1: UNCHANGED (measured best: TJ=64, DMA dbuf, s2-LDS, ~55 us).
// ---------------------------------------------------------------------------
__global__ __launch_bounds__(512, 4) void k_att1(
    const __fp16* __restrict__ hB, const float* __restrict__ s1,
    const float* __restrict__ s2, const unsigned short* __restrict__ mask2,
    const float* __restrict__ bias, __fp16* __restrict__ g1)
{
  constexpr int NRG = 4, NJQ = 2, JLEN = 1024, TJ = 64, NIT = JLEN / TJ;
  constexpr int TILE = TJ * 64;                // 4096 f16 / slot (8 KB)

  __shared__ __fp16 vbuf[NJQ][2][TILE];        // 32 KB
  __shared__ float s2s[N_];                    // 8 KB
  __shared__ float red[8];

  const int tid = threadIdx.x;
  const int w = tid >> 6, l = tid & 63;
  const int quad = l >> 4, c15 = l & 15;
  const int rowg = w % NRG, jq = w / NRG;
  const int tc = rowg * 64 + l;                // [0,256)

  int idx = blockIdx.x;
  const int ig = idx & 31; idx >>= 5;
  const int head = idx & 7;
  const int b = idx >> 3;
  const int i0w = ig * 64 + rowg * 16;

  const float* s1p = s1 + (size_t)(b * 8 + head) * N_;
  const float* s2p = s2 + (size_t)(b * 8 + head) * N_;
  const char* hBp = (const char*)(hB + (size_t)(b * 8 + head) * (N_ / 32) * 2048);
  const unsigned short* mp = mask2 + ((size_t)(b * 128 + (i0w >> 4)) * 32) * 64 + l;

  const int jbase = jq * JLEN;

  auto stage = [&](int j0, int slot) {         // 2 ksteps contiguous = 8 KB
    const char* srcb = hBp + (size_t)(j0 >> 5) * 4096;
    #pragma unroll
    for (int c = 0; c < 2; ++c) {
      int off = (tc + c * 256) * 16;
      __builtin_amdgcn_global_load_lds(
          (const __attribute__((address_space(1))) unsigned int*)(srcb + off),
          (__attribute__((address_space(3))) unsigned int*)
              ((char*)&vbuf[jq][slot][0] + (off - l * 16)), 16, 0, 0);
    }
  };

  stage(jbase, 0);                             // async over the s2 work
  unsigned int mk = mp[(size_t)(jbase >> 6) * 64];

  // stage s2 row + in-block exact row max
  float4 sv = *(const float4*)(s2p + tid * 4);
  *(float4*)&s2s[tid * 4] = sv;
  float lm = fmaxf(fmaxf(sv.x, sv.y), fmaxf(sv.z, sv.w));
  #pragma unroll
  for (int off = 1; off < 64; off <<= 1) lm = fmaxf(lm, __shfl_xor(lm, off, 64));
  if (l == 0) red[w] = lm;
  const float s1v = s1p[i0w + c15];
  __syncthreads();                             // drains slot-0 DMA too
  float s2m = red[0];
  #pragma unroll
  for (int q = 1; q < 8; ++q) s2m = fmaxf(s2m, red[q]);

  const float zm = s1v + s2m;
  const float m = fmaxf(zm, SLOPE_ * zm);      // exact unmasked row max
  const float p = s1v - m;
  const float cq = (SLOPE_ - 1.f) * m;

  f16x8 ones;
  #pragma unroll
  for (int i = 0; i < 8; ++i) ones[i] = (__fp16)1.0f;

  f32x4 acc[4], acc5;
  #pragma unroll
  for (int t = 0; t < 4; ++t) acc[t] = (f32x4){0.f, 0.f, 0.f, 0.f};
  acc5 = (f32x4){0.f, 0.f, 0.f, 0.f};

  for (int it = 0; it < NIT; ++it) {
    const int cur = it & 1;
    const int j0 = jbase + it * TJ;
    unsigned int nk = 0;
    if (it + 1 < NIT) {
      stage(j0 + TJ, cur ^ 1);
      nk = mp[(size_t)((j0 + TJ) >> 6) * 64];
    }

    #pragma unroll
    for (int h = 0; h < 2; ++h) {              // 2 ksteps of 32 j
      const int jk = j0 + h * 32;
      float s2r[8];
      *(float4*)&s2r[0] = *(const float4*)&s2s[jk + quad * 8];
      *(float4*)&s2r[4] = *(const float4*)&s2s[jk + quad * 8 + 4];
      const unsigned int mbyte = (mk >> (8 * h)) & 0xffu;
      float wgt[8];
      #pragma unroll
      for (int k = 0; k < 8; ++k) {
        float t0 = p + s2r[k];
        float t1 = fmaf(SLOPE_, t0, cq);
        float tm = fmaxf(t0, t1);
        float e = __builtin_amdgcn_exp2f(tm);
        int sel = (int)(mbyte << (31 - k)) >> 31;
        union { float f; int i; } u; u.f = e; u.i &= sel;
        wgt[k] = u.f;
      }
      f16x8 a = pack8(wgt);
      acc5 = __builtin_amdgcn_mfma_f32_16x16x32_f16(a, ones, acc5, 0, 0, 0);
      const __fp16* vb = &vbuf[jq][cur][h * 2048];
      #pragma unroll
      for (int t = 0; t < 4; ++t) {
        f16x8 bf = *(const f16x8*)(vb + t * 512 + l * 8);
        acc[t] = __builtin_amdgcn_mfma_f32_16x16x32_f16(a, bf, acc[t], 0, 0, 0);
      }
    }
    mk = nk;
    __syncthreads();
  }

  // combine across the 2 j-chunks (overlay vbuf/s2s)
  auto pacc = (float(*)[16][64])(&vbuf[0][0][0]);   // [NRG][16][64] = 16 KB
  auto pls  = (float(*)[16])(&s2s[0]);              // [NRG][16]
  if (jq == 1) {
    #pragma unroll
    for (int t = 0; t < 4; ++t)
      #pragma unroll
      for (int r = 0; r < 4; ++r)
        pacc[rowg][quad * 4 + r][t * 16 + c15] = acc[t][r];
    if (c15 == 0) {
      #pragma unroll
      for (int r = 0; r < 4; ++r) pls[rowg][quad * 4 + r] = acc5[r];
    }
  }
  __syncthreads();
  if (jq == 0) {
    float Lrow[4];
    #pragma unroll
    for (int r = 0; r < 4; ++r)
      Lrow[r] = acc5[r] + pls[rowg][quad * 4 + r];
    #pragma unroll
    for (int t = 0; t < 4; ++t)
      #pragma unroll
      for (int r = 0; r < 4; ++r)
        acc[t][r] += pacc[rowg][quad * 4 + r][t * 16 + c15];
    float lr[4];
    #pragma unroll
    for (int r = 0; r < 4; ++r) lr[r] = 1.f / Lrow[r];
    #pragma unroll
    for (int t = 0; t < 4; ++t) {
      const float bv = bias[head * 64 + t * 16 + c15];
      #pragma unroll
      for (int r = 0; r < 4; ++r) {
        const int i = i0w + quad * 4 + r;
        float v = acc[t][r] * lr[r] + bv;
        v = (v > 0.f) ? v : expm1f(v);          // elu
        g1[(size_t)(b * N_ + i) * 512 + head * 64 + t * 16 + c15] = (__fp16)v;
      }
    }
  }
}

// ---------------------------------------------------------------------------
// ATT2: barrier-free loop (R17); s1/s2 now summed from gemm2's two f-halves.
// ---------------------------------------------------------------------------
__global__ __launch_bounds__(512, 4) void k_att2(
    const __fp16* __restrict__ hB, const float* __restrict__ s1P,
    const float* __restrict__ s2P, const unsigned short* __restrict__ mask2,
    const float* __restrict__ bias, float* __restrict__ out)
{
  constexpr int NRG = 2, NJQ = 4, JLEN = 512, TJ = 32, NIT = JLEN / TJ;

  __shared__ float s2s[N_];                    // 8 KB
  __shared__ float red[8];
  __shared__ float paccS[NJQ - 1][NRG][16][64];  // 24 KB
  __shared__ float pls[NJQ - 1][NRG][16];

  const int tid = threadIdx.x;
  const int w = tid >> 6, l = tid & 63;
  const int quad = l >> 4, c15 = l & 15;
  const int rowg = w % NRG, jq = w / NRG;

  int idx = blockIdx.x;
  const int ig = idx & 63; idx >>= 6;
  const int fs = idx & 1;
  const int b = idx >> 1;
  const int i0w = ig * 32 + rowg * 16;

  const float* s1p0 = s1P + (size_t)b * N_;
  const float* s1p1 = s1P + (size_t)B_ * N_ + (size_t)b * N_;
  const float* s2p0 = s2P + (size_t)b * N_;
  const float* s2p1 = s2P + (size_t)B_ * N_ + (size_t)b * N_;
  const __fp16* hBp = hB + (size_t)b * 64 * 4096 + fs * 2048 + (size_t)l * 8;
  const unsigned short* mp = mask2 + ((size_t)(b * 128 + (i0w >> 4)) * 32) * 64 + l;

  // stage s2 row (sum of f-halves) + in-block exact row max
  float4 svA = *(const float4*)(s2p0 + tid * 4);
  float4 svB = *(const float4*)(s2p1 + tid * 4);
  float4 sv = make_float4(svA.x + svB.x, svA.y + svB.y,
                          svA.z + svB.z, svA.w + svB.w);
  *(float4*)&s2s[tid * 4] = sv;
  float lm = fmaxf(fmaxf(sv.x, sv.y), fmaxf(sv.z, sv.w));
  #pragma unroll
  for (int off = 1; off < 64; off <<= 1) lm = fmaxf(lm, __shfl_xor(lm, off, 64));
  if (l == 0) red[w] = lm;
  const float s1v = s1p0[i0w + c15] + s1p1[i0w + c15];
  __syncthreads();
  float s2m = red[0];
  #pragma unroll
  for (int q = 1; q < 8; ++q) s2m = fmaxf(s2m, red[q]);

  const float zm = s1v + s2m;
  const float m = fmaxf(zm, SLOPE_ * zm);
  const float p = s1v - m;
  const float cq = (SLOPE_ - 1.f) * m;

  f16x8 ones;
  #pragma unroll
  for (int i = 0; i < 8; ++i) ones[i] = (__fp16)1.0f;

  f32x4 acc[4], acc5;
  #pragma unroll
  for (int t = 0; t < 4; ++t) acc[t] = (f32x4){0.f, 0.f, 0.f, 0.f};
  acc5 = (f32x4){0.f, 0.f, 0.f, 0.f};

  const int jbase = jq * JLEN;
  unsigned int mk = mp[(size_t)(jbase >> 6) * 64];

  for (int it = 0; it < NIT; ++it) {
    const int j0 = jbase + it * TJ;
    const __fp16* vb = hBp + (size_t)(j0 >> 5) * 4096;
    f16x8 bf0 = *(const f16x8*)(vb);
    f16x8 bf1 = *(const f16x8*)(vb + 512);
    f16x8 bf2 = *(const f16x8*)(vb + 1024);
    f16x8 bf3 = *(const f16x8*)(vb + 1536);

    float s2r[8];
    *(float4*)&s2r[0] = *(const float4*)&s2s[j0 + quad * 8];
    *(float4*)&s2r[4] = *(const float4*)&s2s[j0 + quad * 8 + 4];
    const unsigned int mbyte = (mk >> (8 * (it & 1))) & 0xffu;
    if (it & 1) mk = mp[(size_t)((j0 + TJ) >> 6) * 64];   // next ushort

    float wgt[8];
    #pragma unroll
    for (int k = 0; k < 8; ++k) {
      float t0 = p + s2r[k];
      float t1 = fmaf(SLOPE_, t0, cq);
      float tm = fmaxf(t0, t1);
      float e = __builtin_amdgcn_exp2f(tm);
      int sel = (int)(mbyte << (31 - k)) >> 31;
      union { float f; int i; } u; u.f = e; u.i &= sel;
      wgt[k] = u.f;
    }
    f16x8 a = pack8(wgt);
    acc5 = __builtin_amdgcn_mfma_f32_16x16x32_f16(a, ones, acc5, 0, 0, 0);
    acc[0] = __builtin_amdgcn_mfma_f32_16x16x32_f16(a, bf0, acc[0], 0, 0, 0);
    acc[1] = __builtin_amdgcn_mfma_f32_16x16x32_f16(a, bf1, acc[1], 0, 0, 0);
    acc[2] = __builtin_amdgcn_mfma_f32_16x16x32_f16(a, bf2, acc[2], 0, 0, 0);
    acc[3] = __builtin_amdgcn_mfma_f32_16x16x32_f16(a, bf3, acc[3], 0, 0, 0);
  }

  // combine across 4 j-chunks
  if (jq > 0) {
    #pragma unroll
    for (int t = 0; t < 4; ++t)
      #pragma unroll
      for (int r = 0; r < 4; ++r)
        paccS[jq - 1][rowg][quad * 4 + r][t * 16 + c15] = acc[t][r];
    if (c15 == 0) {
      #pragma unroll
      for (int r = 0; r < 4; ++r) pls[jq - 1][rowg][quad * 4 + r] = acc5[r];
    }
  }
  __syncthreads();
  if (jq == 0) {
    float Lrow[4];
    #pragma unroll
    for (int r = 0; r < 4; ++r) Lrow[r] = acc5[r];
    #pragma unroll
    for (int q = 0; q < NJQ - 1; ++q) {
      #pragma unroll
      for (int t = 0; t < 4; ++t)
        #pragma unroll
        for (int r = 0; r < 4; ++r)
          acc[t][r] += paccS[q][rowg][quad * 4 + r][t * 16 + c15];
      #pragma unroll
      for (int r = 0; r < 4; ++r) Lrow[r] += pls[q][rowg][quad * 4 + r];
    }
    float lr[4];
    #pragma unroll
    for (int r = 0; r < 4; ++r) lr[r] = 1.f / Lrow[r];
    #pragma unroll
    for (int t = 0; t < 4; ++t) {
      const float bv = bias[fs * 64 + t * 16 + c15];
      #pragma unroll
      for (int r = 0; r < 4; ++r) {
        const int i = i0w + quad * 4 + r;
        float v = acc[t][r] * lr[r] + bv;
        out[(size_t)(b * N_ + i) * 128 + fs * 64 + t * 16 + c15] = fmaxf(v, 0.f);
      }
    }
  }
}

// ---------------------------------------------------------------------------
extern "C" void kernel_launch(void* const* d_in, const int* in_sizes, int n_in,
                              void* d_out, int out_size, void* d_ws, size_t ws_size,
                              hipStream_t stream) {
  const float* x   = (const float*)d_in[0];
  const int*   adj = (const int*)d_in[1];
  const float* Wh  = (const float*)d_in[2];
  const float* ah  = (const float*)d_in[3];
  const float* bh  = (const float*)d_in[4];
  const float* Wo  = (const float*)d_in[5];
  const float* ao  = (const float*)d_in[6];
  const float* bo  = (const float*)d_in[7];
  float* out = (float*)d_out;

  float* ws   = (float*)d_ws;
  float* s1h  = ws;                                   // B*8*N
  float* s2h  = s1h  + (size_t)B_ * NHEADS_ * N_;
  float* s1oP = s2h  + (size_t)B_ * NHEADS_ * N_;     // 2*B*N (f-halves)
  float* s2oP = s1oP + (size_t)2 * B_ * N_;           // 2*B*N
  __fp16* g1  = (__fp16*)(s2oP + (size_t)2 * B_ * N_); // B*N*512 f16 (8 MB)
  __fp16* hB1 = g1  + (size_t)B_ * N_ * 512;          // 8 MB
  __fp16* hB2 = hB1 + (size_t)B_ * NHEADS_ * N_ * 64; // 2 MB
  __fp16* WhB = hB2 + (size_t)B_ * N_ * 128;          // 256 KB
  __fp16* WoB = WhB + (size_t)8 * 256 * 64;           // 128 KB
  unsigned short* mask2 = (unsigned short*)(WoB + (size_t)512 * 128); // 2 MB

  k_prep<<<4192, 256, 0, stream>>>(adj, mask2, Wh, WhB, Wo, WoB);
  k_gemm1<<<B_ * 128 * 4, 256, 0, stream>>>(x, WhB, ah, hB1, s1h, s2h);
  k_att1<<<B_ * NHEADS_ * (N_ / 64), 512, 0, stream>>>(
      hB1, s1h, s2h, mask2, bh, g1);
  k_gemm2<<<B_ * 128 * 2, 256, 0, stream>>>(g1, WoB, ao, hB2, s1oP, s2oP);
  k_att2<<<B_ * 2 * (N_ / 32), 512, 0, stream>>>(
      hB2, s1oP, s2oP, mask2, bo, out);
}

// Round 19
// 196.148 us; speedup vs baseline: 1.0166x; 1.0166x over previous
//
#include <hip/hip_runtime.h>

constexpr int B_ = 4;
constexpr int N_ = 2048;
constexpr int NFEAT_ = 256;
constexpr int NHEADS_ = 8;
constexpr float SLOPE_ = 0.1f;
constexpr float L2E = 1.4426950408889634f;   // log2(e)

typedef __attribute__((ext_vector_type(8))) __fp16 f16x8;
typedef __attribute__((ext_vector_type(4))) __fp16 f16x4;
typedef __attribute__((ext_vector_type(2))) __fp16 f16x2;
typedef __attribute__((ext_vector_type(4))) float f32x4;

__device__ __forceinline__ f16x8 pack8(const float* v) {
  union { f16x2 h2[4]; f16x8 h8; } u;
  u.h2[0] = __builtin_amdgcn_cvt_pkrtz(v[0], v[1]);
  u.h2[1] = __builtin_amdgcn_cvt_pkrtz(v[2], v[3]);
  u.h2[2] = __builtin_amdgcn_cvt_pkrtz(v[4], v[5]);
  u.h2[3] = __builtin_amdgcn_cvt_pkrtz(v[6], v[7]);
  return u.h8;
}
__device__ __forceinline__ f16x4 pack4(float a, float b, float c, float d) {
  union { f16x2 h2[2]; f16x4 h4; } u;
  u.h2[0] = __builtin_amdgcn_cvt_pkrtz(a, b);
  u.h2[1] = __builtin_amdgcn_cvt_pkrtz(c, d);
  return u.h4;
}

// ---------------------------------------------------------------------------
// Weight prep (must precede gemm1): [0,64) Wh pack, [64,96) Wo pack.
// ---------------------------------------------------------------------------
__global__ __launch_bounds__(256) void k_prepw(
    const float* __restrict__ Wh, __fp16* __restrict__ WhB,
    const float* __restrict__ Wo, __fp16* __restrict__ WoB)
{
  const int bid = blockIdx.x;
  const int l = threadIdx.x & 63;
  if (bid < 64) {
    int s = (int)((bid * 256 + threadIdx.x) >> 6);            // 0..255
    int h = s >> 5, ks = (s >> 2) & 7, ft = s & 3;
    const float* src = Wh + ((size_t)h * 256 + ks * 32 + (l >> 4) * 8) * 64 + ft * 16 + (l & 15);
    float v[8];
    #pragma unroll
    for (int j = 0; j < 8; ++j) v[j] = src[(size_t)j * 64];
    *(f16x8*)(WhB + (size_t)s * 512 + l * 8) = pack8(v);
  } else {
    int s = (int)(((bid - 64) * 256 + threadIdx.x) >> 6);     // 0..127
    int ks = s >> 3, ft = s & 7;
    const float* src = Wo + ((size_t)ks * 32 + (l >> 4) * 8) * 128 + ft * 16 + (l & 15);
    float v[8];
    #pragma unroll
    for (int j = 0; j < 8; ++j) v[j] = src[(size_t)j * 128];
    *(f16x8*)(WoB + (size_t)s * 512 + l * 8) = pack8(v);
  }
}

// ---------------------------------------------------------------------------
// FUSED gemm1 + packmask: blocks [0,512) = GEMM1 (R17 form: 16 n-rows x all
// 512 f); blocks [512,4608) = adj->mask2 pack. The two are data-independent
// (gemm1 reads WhB from k_prepw, not mask2), so the HBM-bound adj read
// overlaps gemm1's MFMA work instead of serializing (~13 us + 1 launch gap).
// gemm1 blocks dispatched first (long pole starts immediately).
// ---------------------------------------------------------------------------
__global__ __launch_bounds__(256, 4) void k_g1m(
    const float* __restrict__ x, const __fp16* __restrict__ WhB,
    const float* __restrict__ ah,
    __fp16* __restrict__ hB1, float* __restrict__ s1h, float* __restrict__ s2h,
    const int* __restrict__ adj, unsigned short* __restrict__ mask2)
{
  constexpr int XP = 264;
  __shared__ __fp16 xs[16 * XP];
  __shared__ __fp16 hT[512 * 16];

  const int t = threadIdx.x;
  const int bid0 = blockIdx.x;

  if (bid0 >= 512) {                           // ---- packmask path ----
    const int l = t & 63;
    const size_t gw = ((size_t)(bid0 - 512) * 256 + t) >> 6;
    const int jt = (int)(gw & 31);
    const int ig16 = (int)((gw >> 5) & 127);
    const int b = (int)(gw >> 12);
    const int q = l >> 4, c15 = l & 15;
    const int* base = adj + ((size_t)b * N_ + ig16 * 16) * N_ + jt * 64 + l;
    unsigned int msk = 0;
    #pragma unroll
    for (int r = 0; r < 16; ++r) {
      int a = base[(size_t)r * N_];
      unsigned long long bal = __ballot(a > 0);
      unsigned int v = (unsigned int)((bal >> (q * 8)) & 0xffull)
                     | ((unsigned int)((bal >> (q * 8 + 32)) & 0xffull) << 8);
      if (r == c15) msk = v;
    }
    mask2[gw * 64 + l] = (unsigned short)msk;
    return;
  }

  // ---- gemm1 path (R17 form) ----
  const int bid = bid0;
  const int b = bid >> 7;
  const int n0 = (bid & 127) * 16;

  {  // stage x -> f16
    int r = t >> 4, k0 = (t & 15) * 16;
    const float* src = x + ((size_t)(b * N_) + n0 + r) * NFEAT_ + k0;
    float v0[8], v1[8];
    *(float4*)&v0[0] = *(const float4*)(src);
    *(float4*)&v0[4] = *(const float4*)(src + 4);
    *(float4*)&v1[0] = *(const float4*)(src + 8);
    *(float4*)&v1[4] = *(const float4*)(src + 12);
    *(f16x8*)&xs[r * XP + k0] = pack8(v0);
    *(f16x8*)&xs[r * XP + k0 + 8] = pack8(v1);
  }
  __syncthreads();

  const int w = t >> 6, l = t & 63;
  const int quad = l >> 4, c15 = l & 15;

  f32x4 acc[8];
  #pragma unroll
  for (int i = 0; i < 8; ++i) acc[i] = (f32x4){0.f, 0.f, 0.f, 0.f};

  for (int ks = 0; ks < 8; ++ks) {
    f16x8 af = *(const f16x8*)&xs[c15 * XP + ks * 32 + quad * 8];
    #pragma unroll
    for (int tt = 0; tt < 8; ++tt) {
      int hl = tt >> 2, ft = tt & 3;
      f16x8 bf = *(const f16x8*)(WhB +
          ((((size_t)(2 * w + hl) * 8 + ks) * 4 + ft) * 512) + l * 8);
      acc[tt] = __builtin_amdgcn_mfma_f32_16x16x32_f16(af, bf, acc[tt], 0, 0, 0);
    }
  }

  #pragma unroll
  for (int hl = 0; hl < 2; ++hl) {
    int head = 2 * w + hl;
    float a1v[4], a2v[4];
    #pragma unroll
    for (int ft = 0; ft < 4; ++ft) {
      a1v[ft] = ah[head * 128 + ft * 16 + c15] * L2E;
      a2v[ft] = ah[head * 128 + 64 + ft * 16 + c15] * L2E;
    }
    #pragma unroll
    for (int r = 0; r < 4; ++r) {
      float v1 = 0.f, v2 = 0.f;
      #pragma unroll
      for (int ft = 0; ft < 4; ++ft) {
        v1 = fmaf(acc[hl * 4 + ft][r], a1v[ft], v1);
        v2 = fmaf(acc[hl * 4 + ft][r], a2v[ft], v2);
      }
      #pragma unroll
      for (int off = 1; off < 16; off <<= 1) {
        v1 += __shfl_xor(v1, off, 64);
        v2 += __shfl_xor(v2, off, 64);
      }
      if (c15 == 0) {
        s1h[(size_t)(b * NHEADS_ + head) * N_ + n0 + quad * 4 + r] = v1;
        s2h[(size_t)(b * NHEADS_ + head) * N_ + n0 + quad * 4 + r] = v2;
      }
    }
  }

  #pragma unroll
  for (int tt = 0; tt < 8; ++tt) {
    int f = (2 * w + (tt >> 2)) * 64 + (tt & 3) * 16 + c15;
    *(f16x4*)&hT[f * 16 + quad * 4] =
        pack4(acc[tt][0], acc[tt][1], acc[tt][2], acc[tt][3]);
  }
  __syncthreads();

  const int base_oct = (n0 >> 3) & 3;
  #pragma unroll
  for (int q = 0; q < 4; ++q) {
    int s = t + q * 256;
    int c15v = s & 15, oct = (s >> 4) & 1, ft = (s >> 5) & 3, head = s >> 7;
    f16x8 v = *(const f16x8*)&hT[(head * 64 + ft * 16 + c15v) * 16 + oct * 8];
    int lane0 = (base_oct + oct) * 16 + c15v;
    *(f16x8*)(hB1 +
        ((((size_t)(b * NHEADS_ + head) * 64 + (n0 >> 5)) * 4 + ft) * 512) + lane0 * 8) = v;
  }
}

// ---------------------------------------------------------------------------
// GEMM2 (MFMA, R17 form): block = 16 n-rows x 128 f, 256 thr = 4 waves.
// ---------------------------------------------------------------------------
__global__ __launch_bounds__(256, 4) void k_gemm2(
    const __fp16* __restrict__ g1, const __fp16* __restrict__ WoB,
    const float* __restrict__ ao,
    __fp16* __restrict__ hB2, float* __restrict__ s1o, float* __restrict__ s2o)
{
  constexpr int GP = 520;
  __shared__ __fp16 gs[16 * GP];
  __shared__ __fp16 hT[128 * 16];
  __shared__ float sd1[4][16], sd2[4][16];

  const int t = threadIdx.x;
  const int bid = blockIdx.x;
  const int b = bid >> 7;
  const int n0 = (bid & 127) * 16;

  {
    int r = t >> 4, k0 = (t & 15) * 32;
    const __fp16* src = g1 + ((size_t)(b * N_) + n0 + r) * 512 + k0;
    #pragma unroll
    for (int i = 0; i < 4; ++i)
      *(f16x8*)&gs[r * GP + k0 + i * 8] = *(const f16x8*)(src + i * 8);
  }
  __syncthreads();

  const int w = t >> 6, l = t & 63;
  const int quad = l >> 4, c15 = l & 15;

  f32x4 acc[2];
  acc[0] = (f32x4){0.f, 0.f, 0.f, 0.f};
  acc[1] = (f32x4){0.f, 0.f, 0.f, 0.f};

  for (int ks = 0; ks < 16; ++ks) {
    f16x8 af = *(const f16x8*)&gs[c15 * GP + ks * 32 + quad * 8];
    #pragma unroll
    for (int tt = 0; tt < 2; ++tt) {
      int ft = 2 * w + tt;
      f16x8 bf = *(const f16x8*)(WoB + (((size_t)ks * 8 + ft) * 512) + l * 8);
      acc[tt] = __builtin_amdgcn_mfma_f32_16x16x32_f16(af, bf, acc[tt], 0, 0, 0);
    }
  }

  {
    float a1v[2], a2v[2];
    #pragma unroll
    for (int tt = 0; tt < 2; ++tt) {
      int f = (2 * w + tt) * 16 + c15;
      a1v[tt] = ao[f] * L2E;
      a2v[tt] = ao[128 + f] * L2E;
    }
    #pragma unroll
    for (int r = 0; r < 4; ++r) {
      float v1 = acc[0][r] * a1v[0] + acc[1][r] * a1v[1];
      float v2 = acc[0][r] * a2v[0] + acc[1][r] * a2v[1];
      #pragma unroll
      for (int off = 1; off < 16; off <<= 1) {
        v1 += __shfl_xor(v1, off, 64);
        v2 += __shfl_xor(v2, off, 64);
      }
      if (c15 == 0) { sd1[w][quad * 4 + r] = v1; sd2[w][quad * 4 + r] = v2; }
    }
  }

  #pragma unroll
  for (int tt = 0; tt < 2; ++tt) {
    int f = (2 * w + tt) * 16 + c15;
    *(f16x4*)&hT[f * 16 + quad * 4] =
        pack4(acc[tt][0], acc[tt][1], acc[tt][2], acc[tt][3]);
  }
  __syncthreads();

  if (t < 16)
    s1o[(size_t)b * N_ + n0 + t] = sd1[0][t] + sd1[1][t] + sd1[2][t] + sd1[3][t];
  else if (t < 32) {
    int rr = t - 16;
    s2o[(size_t)b * N_ + n0 + rr] = sd2[0][rr] + sd2[1][rr] + sd2[2][rr] + sd2[3][rr];
  }

  {
    int c15v = t & 15, oct = (t >> 4) & 1, ft = t >> 5;
    f16x8 v = *(const f16x8*)&hT[(ft * 16 + c15v) * 16 + oct * 8];
    int base_oct = (n0 >> 3) & 3;
    int lane0 = (base_oct + oct) * 16 + c15v;
    *(f16x8*)(hB2 +
        (((size_t)(b * 64 + (n0 >> 5)) * 8 + ft) * 512) + lane0 * 8) = v;
  }
}

// ---------------------------------------------------------------------------
// ATT1: UNCHANGED (measured best: TJ=64, DMA dbuf, s2-LDS, ~55 us).
// ---------------------------------------------------------------------------
__global__ __launch_bounds__(512, 4) void k_att1(
    const __fp16* __restrict__ hB, const float* __restrict__ s1,
    const float* __restrict__ s2, const unsigned short* __restrict__ mask2,
    const float* __restrict__ bias, __fp16* __restrict__ g1)
{
  constexpr int NRG = 4, NJQ = 2, JLEN = 1024, TJ = 64, NIT = JLEN / TJ;
  constexpr int TILE = TJ * 64;                // 4096 f16 / slot (8 KB)

  __shared__ __fp16 vbuf[NJQ][2][TILE];        // 32 KB
  __shared__ float s2s[N_];                    // 8 KB
  __shared__ float red[8];

  const int tid = threadIdx.x;
  const int w = tid >> 6, l = tid & 63;
  const int quad = l >> 4, c15 = l & 15;
  const int rowg = w % NRG, jq = w / NRG;
  const int tc = rowg * 64 + l;                // [0,256)

  int idx = blockIdx.x;
  const int ig = idx & 31; idx >>= 5;
  const int head = idx & 7;
  const int b = idx >> 3;
  const int i0w = ig * 64 + rowg * 16;

  const float* s1p = s1 + (size_t)(b * 8 + head) * N_;
  const float* s2p = s2 + (size_t)(b * 8 + head) * N_;
  const char* hBp = (const char*)(hB + (size_t)(b * 8 + head) * (N_ / 32) * 2048);
  const unsigned short* mp = mask2 + ((size_t)(b * 128 + (i0w >> 4)) * 32) * 64 + l;

  const int jbase = jq * JLEN;

  auto stage = [&](int j0, int slot) {         // 2 ksteps contiguous = 8 KB
    const char* srcb = hBp + (size_t)(j0 >> 5) * 4096;
    #pragma unroll
    for (int c = 0; c < 2; ++c) {
      int off = (tc + c * 256) * 16;
      __builtin_amdgcn_global_load_lds(
          (const __attribute__((address_space(1))) unsigned int*)(srcb + off),
          (__attribute__((address_space(3))) unsigned int*)
              ((char*)&vbuf[jq][slot][0] + (off - l * 16)), 16, 0, 0);
    }
  };

  stage(jbase, 0);                             // async over the s2 work
  unsigned int mk = mp[(size_t)(jbase >> 6) * 64];

  // stage s2 row + in-block exact row max
  float4 sv = *(const float4*)(s2p + tid * 4);
  *(float4*)&s2s[tid * 4] = sv;
  float lm = fmaxf(fmaxf(sv.x, sv.y), fmaxf(sv.z, sv.w));
  #pragma unroll
  for (int off = 1; off < 64; off <<= 1) lm = fmaxf(lm, __shfl_xor(lm, off, 64));
  if (l == 0) red[w] = lm;
  const float s1v = s1p[i0w + c15];
  __syncthreads();                             // drains slot-0 DMA too
  float s2m = red[0];
  #pragma unroll
  for (int q = 1; q < 8; ++q) s2m = fmaxf(s2m, red[q]);

  const float zm = s1v + s2m;
  const float m = fmaxf(zm, SLOPE_ * zm);      // exact unmasked row max
  const float p = s1v - m;
  const float cq = (SLOPE_ - 1.f) * m;

  f16x8 ones;
  #pragma unroll
  for (int i = 0; i < 8; ++i) ones[i] = (__fp16)1.0f;

  f32x4 acc[4], acc5;
  #pragma unroll
  for (int t = 0; t < 4; ++t) acc[t] = (f32x4){0.f, 0.f, 0.f, 0.f};
  acc5 = (f32x4){0.f, 0.f, 0.f, 0.f};

  for (int it = 0; it < NIT; ++it) {
    const int cur = it & 1;
    const int j0 = jbase + it * TJ;
    unsigned int nk = 0;
    if (it + 1 < NIT) {
      stage(j0 + TJ, cur ^ 1);
      nk = mp[(size_t)((j0 + TJ) >> 6) * 64];
    }

    #pragma unroll
    for (int h = 0; h < 2; ++h) {              // 2 ksteps of 32 j
      const int jk = j0 + h * 32;
      float s2r[8];
      *(float4*)&s2r[0] = *(const float4*)&s2s[jk + quad * 8];
      *(float4*)&s2r[4] = *(const float4*)&s2s[jk + quad * 8 + 4];
      const unsigned int mbyte = (mk >> (8 * h)) & 0xffu;
      float wgt[8];
      #pragma unroll
      for (int k = 0; k < 8; ++k) {
        float t0 = p + s2r[k];
        float t1 = fmaf(SLOPE_, t0, cq);
        float tm = fmaxf(t0, t1);
        float e = __builtin_amdgcn_exp2f(tm);
        int sel = (int)(mbyte << (31 - k)) >> 31;
        union { float f; int i; } u; u.f = e; u.i &= sel;
        wgt[k] = u.f;
      }
      f16x8 a = pack8(wgt);
      acc5 = __builtin_amdgcn_mfma_f32_16x16x32_f16(a, ones, acc5, 0, 0, 0);
      const __fp16* vb = &vbuf[jq][cur][h * 2048];
      #pragma unroll
      for (int t = 0; t < 4; ++t) {
        f16x8 bf = *(const f16x8*)(vb + t * 512 + l * 8);
        acc[t] = __builtin_amdgcn_mfma_f32_16x16x32_f16(a, bf, acc[t], 0, 0, 0);
      }
    }
    mk = nk;
    __syncthreads();
  }

  // combine across the 2 j-chunks (overlay vbuf/s2s)
  auto pacc = (float(*)[16][64])(&vbuf[0][0][0]);   // [NRG][16][64] = 16 KB
  auto pls  = (float(*)[16])(&s2s[0]);              // [NRG][16]
  if (jq == 1) {
    #pragma unroll
    for (int t = 0; t < 4; ++t)
      #pragma unroll
      for (int r = 0; r < 4; ++r)
        pacc[rowg][quad * 4 + r][t * 16 + c15] = acc[t][r];
    if (c15 == 0) {
      #pragma unroll
      for (int r = 0; r < 4; ++r) pls[rowg][quad * 4 + r] = acc5[r];
    }
  }
  __syncthreads();
  if (jq == 0) {
    float Lrow[4];
    #pragma unroll
    for (int r = 0; r < 4; ++r)
      Lrow[r] = acc5[r] + pls[rowg][quad * 4 + r];
    #pragma unroll
    for (int t = 0; t < 4; ++t)
      #pragma unroll
      for (int r = 0; r < 4; ++r)
        acc[t][r] += pacc[rowg][quad * 4 + r][t * 16 + c15];
    float lr[4];
    #pragma unroll
    for (int r = 0; r < 4; ++r) lr[r] = 1.f / Lrow[r];
    #pragma unroll
    for (int t = 0; t < 4; ++t) {
      const float bv = bias[head * 64 + t * 16 + c15];
      #pragma unroll
      for (int r = 0; r < 4; ++r) {
        const int i = i0w + quad * 4 + r;
        float v = acc[t][r] * lr[r] + bv;
        v = (v > 0.f) ? v : expm1f(v);          // elu
        g1[(size_t)(b * N_ + i) * 512 + head * 64 + t * 16 + c15] = (__fp16)v;
      }
    }
  }
}

// ---------------------------------------------------------------------------
// ATT2: barrier-free loop (R17 form).
// ---------------------------------------------------------------------------
__global__ __launch_bounds__(512, 4) void k_att2(
    const __fp16* __restrict__ hB, const float* __restrict__ s1,
    const float* __restrict__ s2, const unsigned short* __restrict__ mask2,
    const float* __restrict__ bias, float* __restrict__ out)
{
  constexpr int NRG = 2, NJQ = 4, JLEN = 512, TJ = 32, NIT = JLEN / TJ;

  __shared__ float s2s[N_];                    // 8 KB
  __shared__ float red[8];
  __shared__ float paccS[NJQ - 1][NRG][16][64];  // 24 KB
  __shared__ float pls[NJQ - 1][NRG][16];

  const int tid = threadIdx.x;
  const int w = tid >> 6, l = tid & 63;
  const int quad = l >> 4, c15 = l & 15;
  const int rowg = w % NRG, jq = w / NRG;

  int idx = blockIdx.x;
  const int ig = idx & 63; idx >>= 6;
  const int fs = idx & 1;
  const int b = idx >> 1;
  const int i0w = ig * 32 + rowg * 16;

  const float* s1p = s1 + (size_t)b * N_;
  const float* s2p = s2 + (size_t)b * N_;
  const __fp16* hBp = hB + (size_t)b * 64 * 4096 + fs * 2048 + (size_t)l * 8;
  const unsigned short* mp = mask2 + ((size_t)(b * 128 + (i0w >> 4)) * 32) * 64 + l;

  // stage s2 row + in-block exact row max
  float4 sv = *(const float4*)(s2p + tid * 4);
  *(float4*)&s2s[tid * 4] = sv;
  float lm = fmaxf(fmaxf(sv.x, sv.y), fmaxf(sv.z, sv.w));
  #pragma unroll
  for (int off = 1; off < 64; off <<= 1) lm = fmaxf(lm, __shfl_xor(lm, off, 64));
  if (l == 0) red[w] = lm;
  const float s1v = s1p[i0w + c15];
  __syncthreads();
  float s2m = red[0];
  #pragma unroll
  for (int q = 1; q < 8; ++q) s2m = fmaxf(s2m, red[q]);

  const float zm = s1v + s2m;
  const float m = fmaxf(zm, SLOPE_ * zm);
  const float p = s1v - m;
  const float cq = (SLOPE_ - 1.f) * m;

  f16x8 ones;
  #pragma unroll
  for (int i = 0; i < 8; ++i) ones[i] = (__fp16)1.0f;

  f32x4 acc[4], acc5;
  #pragma unroll
  for (int t = 0; t < 4; ++t) acc[t] = (f32x4){0.f, 0.f, 0.f, 0.f};
  acc5 = (f32x4){0.f, 0.f, 0.f, 0.f};

  const int jbase = jq * JLEN;
  unsigned int mk = mp[(size_t)(jbase >> 6) * 64];

  for (int it = 0; it < NIT; ++it) {
    const int j0 = jbase + it * TJ;
    const __fp16* vb = hBp + (size_t)(j0 >> 5) * 4096;
    f16x8 bf0 = *(const f16x8*)(vb);
    f16x8 bf1 = *(const f16x8*)(vb + 512);
    f16x8 bf2 = *(const f16x8*)(vb + 1024);
    f16x8 bf3 = *(const f16x8*)(vb + 1536);

    float s2r[8];
    *(float4*)&s2r[0] = *(const float4*)&s2s[j0 + quad * 8];
    *(float4*)&s2r[4] = *(const float4*)&s2s[j0 + quad * 8 + 4];
    const unsigned int mbyte = (mk >> (8 * (it & 1))) & 0xffu;
    if (it & 1) mk = mp[(size_t)((j0 + TJ) >> 6) * 64];   // next ushort

    float wgt[8];
    #pragma unroll
    for (int k = 0; k < 8; ++k) {
      float t0 = p + s2r[k];
      float t1 = fmaf(SLOPE_, t0, cq);
      float tm = fmaxf(t0, t1);
      float e = __builtin_amdgcn_exp2f(tm);
      int sel = (int)(mbyte << (31 - k)) >> 31;
      union { float f; int i; } u; u.f = e; u.i &= sel;
      wgt[k] = u.f;
    }
    f16x8 a = pack8(wgt);
    acc5 = __builtin_amdgcn_mfma_f32_16x16x32_f16(a, ones, acc5, 0, 0, 0);
    acc[0] = __builtin_amdgcn_mfma_f32_16x16x32_f16(a, bf0, acc[0], 0, 0, 0);
    acc[1] = __builtin_amdgcn_mfma_f32_16x16x32_f16(a, bf1, acc[1], 0, 0, 0);
    acc[2] = __builtin_amdgcn_mfma_f32_16x16x32_f16(a, bf2, acc[2], 0, 0, 0);
    acc[3] = __builtin_amdgcn_mfma_f32_16x16x32_f16(a, bf3, acc[3], 0, 0, 0);
  }

  // combine across 4 j-chunks
  if (jq > 0) {
    #pragma unroll
    for (int t = 0; t < 4; ++t)
      #pragma unroll
      for (int r = 0; r < 4; ++r)
        paccS[jq - 1][rowg][quad * 4 + r][t * 16 + c15] = acc[t][r];
    if (c15 == 0) {
      #pragma unroll
      for (int r = 0; r < 4; ++r) pls[jq - 1][rowg][quad * 4 + r] = acc5[r];
    }
  }
  __syncthreads();
  if (jq == 0) {
    float Lrow[4];
    #pragma unroll
    for (int r = 0; r < 4; ++r) Lrow[r] = acc5[r];
    #pragma unroll
    for (int q = 0; q < NJQ - 1; ++q) {
      #pragma unroll
      for (int t = 0; t < 4; ++t)
        #pragma unroll
        for (int r = 0; r < 4; ++r)
          acc[t][r] += paccS[q][rowg][quad * 4 + r][t * 16 + c15];
      #pragma unroll
      for (int r = 0; r < 4; ++r) Lrow[r] += pls[q][rowg][quad * 4 + r];
    }
    float lr[4];
    #pragma unroll
    for (int r = 0; r < 4; ++r) lr[r] = 1.f / Lrow[r];
    #pragma unroll
    for (int t = 0; t < 4; ++t) {
      const float bv = bias[fs * 64 + t * 16 + c15];
      #pragma unroll
      for (int r = 0; r < 4; ++r) {
        const int i = i0w + quad * 4 + r;
        float v = acc[t][r] * lr[r] + bv;
        out[(size_t)(b * N_ + i) * 128 + fs * 64 + t * 16 + c15] = fmaxf(v, 0.f);
      }
    }
  }
}

// ---------------------------------------------------------------------------
extern "C" void kernel_launch(void* const* d_in, const int* in_sizes, int n_in,
                              void* d_out, int out_size, void* d_ws, size_t ws_size,
                              hipStream_t stream) {
  const float* x   = (const float*)d_in[0];
  const int*   adj = (const int*)d_in[1];
  const float* Wh  = (const float*)d_in[2];
  const float* ah  = (const float*)d_in[3];
  const float* bh  = (const float*)d_in[4];
  const float* Wo  = (const float*)d_in[5];
  const float* ao  = (const float*)d_in[6];
  const float* bo  = (const float*)d_in[7];
  float* out = (float*)d_out;

  float* ws   = (float*)d_ws;
  float* s1h  = ws;                                   // B*8*N
  float* s2h  = s1h  + (size_t)B_ * NHEADS_ * N_;
  float* s1o  = s2h  + (size_t)B_ * NHEADS_ * N_;     // B*N
  float* s2o  = s1o  + (size_t)B_ * N_;
  __fp16* g1  = (__fp16*)(s2o + (size_t)B_ * N_);     // B*N*512 f16 (8 MB)
  __fp16* hB1 = g1  + (size_t)B_ * N_ * 512;          // 8 MB
  __fp16* hB2 = hB1 + (size_t)B_ * NHEADS_ * N_ * 64; // 2 MB
  __fp16* WhB = hB2 + (size_t)B_ * N_ * 128;          // 256 KB
  __fp16* WoB = WhB + (size_t)8 * 256 * 64;           // 128 KB
  unsigned short* mask2 = (unsigned short*)(WoB + (size_t)512 * 128); // 2 MB

  k_prepw<<<96, 256, 0, stream>>>(Wh, WhB, Wo, WoB);
  k_g1m<<<512 + 4096, 256, 0, stream>>>(x, WhB, ah, hB1, s1h, s2h, adj, mask2);
  k_att1<<<B_ * NHEADS_ * (N_ / 64), 512, 0, stream>>>(
      hB1, s1h, s2h, mask2, bh, g1);
  k_gemm2<<<B_ * (N_ / 16), 256, 0, stream>>>(g1, WoB, ao, hB2, s1o, s2o);
  k_att2<<<B_ * 2 * (N_ / 32), 512, 0, stream>>>(
      hB2, s1o, s2o, mask2, bo, out);
}